// Round 7
// baseline (320.644 us; speedup 1.0000x reference)
//
#include <hip/hip_runtime.h>

#define N 4096
#define C 64
#define B 4
#define LOG2E 1.44269504088896340736f

typedef __attribute__((ext_vector_type(8))) short short8;
typedef __attribute__((ext_vector_type(4))) short s16x4;
typedef __attribute__((ext_vector_type(4))) float f32x4;
typedef unsigned long long u64;

#define MFMA16(a, b, c) __builtin_amdgcn_mfma_f32_16x16x32_bf16(a, b, c, 0, 0, 0)

__device__ __forceinline__ short f2bf(float f) {
    unsigned u = __builtin_bit_cast(unsigned, f);
    u += 0x7fffu + ((u >> 16) & 1u);   // RNE; inputs finite
    return (short)(u >> 16);
}
__device__ __forceinline__ unsigned pk2bf(float a, float b) {
    unsigned lo = (unsigned)(unsigned short)f2bf(a);
    unsigned hi = (unsigned)(unsigned short)f2bf(b);
    return lo | (hi << 16);
}

// -------- Fused Phase A: blocks [0,N/4) = projection; blocks [N/4, N/2) = adjacency mask --------
// a_srcb and e2 are PRE-SCALED by log2e so attn can use exp2 directly.
__global__ __launch_bounds__(256) void proj_mask_kernel(
    const float* __restrict__ x,       // B,N,C
    const float* __restrict__ proj_w,  // N,C,C
    const float* __restrict__ proj_b,  // N,C
    const float* __restrict__ a_w,     // N,2C
    const float* __restrict__ dist,    // N,N
    short* __restrict__ h_bf,          // B,N,C
    short* __restrict__ a_srcb,        // N,C  (x log2e)
    float* __restrict__ e2,            // B,N  (x log2e)
    u64* __restrict__ msk)             // N x N/64
{
    __shared__ float lds_w[4][64 * 64];   // 64 KB (proj branch only)
    __shared__ float lds_x[4][B][C];

    const int tid = threadIdx.x;
    const int wave = tid >> 6;
    const int lane = tid & 63;

    if (blockIdx.x >= N / 4) {
        // ---- mask branch ----
        const int i = (blockIdx.x - N / 4) * 4 + wave;
        const float* row = dist + (size_t)i * N;
#pragma unroll 8
        for (int jb = 0; jb < N / 64; jb++) {
            float d = row[jb * 64 + lane];
            u64 m = __ballot(d > 0.f && d < 0.5f);
            int dj = i - jb * 64;
            if (dj >= 0 && dj < 64) m |= (1ull << dj);
            if (lane == 0) msk[(size_t)i * (N / 64) + jb] = m;
        }
        return;
    }

    // ---- proj branch ----
    const int n = blockIdx.x * 4 + wave;
    const float* Wn = proj_w + (size_t)n * C * C;

    float4 wbuf[16];
#pragma unroll
    for (int it = 0; it < 16; it++)
        wbuf[it] = *(const float4*)(Wn + it * 256 + lane * 4);
#pragma unroll
    for (int b = 0; b < B; b++)
        lds_x[wave][b][lane] = x[((size_t)b * N + n) * C + lane];
#pragma unroll
    for (int it = 0; it < 16; it++)
        *(float4*)&lds_w[wave][it * 256 + lane * 4] = wbuf[it];

    const int o = lane;
    float acc[B];
    float pb = proj_b[(size_t)n * C + o];
#pragma unroll
    for (int b = 0; b < B; b++) acc[b] = pb;

#pragma unroll 4
    for (int c4 = 0; c4 < C; c4 += 4) {
        f32x4 xq[B];
#pragma unroll
        for (int b = 0; b < B; b++) xq[b] = *(const f32x4*)&lds_x[wave][b][c4];
#pragma unroll
        for (int k = 0; k < 4; k++) {
            float w = lds_w[wave][(c4 + k) * C + o];
#pragma unroll
            for (int b = 0; b < B; b++) acc[b] = fmaf(xq[b][k], w, acc[b]);
        }
    }

    float adst = a_w[(size_t)n * (2 * C) + C + o] * LOG2E;
    a_srcb[(size_t)n * C + o] = f2bf(a_w[(size_t)n * (2 * C) + o] * LOG2E);
#pragma unroll
    for (int b = 0; b < B; b++) {
        h_bf[((size_t)b * N + n) * C + o] = f2bf(acc[b]);
        float prod = acc[b] * adst;
#pragma unroll
        for (int off = 32; off; off >>= 1) prod += __shfl_xor(prod, off, 64);
        if (lane == 0) e2[b * N + n] = prod;
    }
}

// -------- h (B,N,C) -> hT (B,C,N) --------
__global__ __launch_bounds__(256) void transpose_kernel(const short* __restrict__ h_bf,
                                                        short* __restrict__ hT_bf) {
    __shared__ short tile[64][72];
    const int t = threadIdx.x;
    const int b = blockIdx.y;
    const int n0 = blockIdx.x * 64;
    {
        int r = t >> 2, cs = (t & 3) * 16;
        const short* src = h_bf + ((size_t)b * N + n0 + r) * C + cs;
#pragma unroll
        for (int q = 0; q < 4; q++)
            *(s16x4*)&tile[r][cs + q * 4] = *(const s16x4*)(src + q * 4);
    }
    __syncthreads();
    {
        int c = t >> 2, ns = (t & 3) * 16;
        short v[16];
#pragma unroll
        for (int k = 0; k < 16; k++) v[k] = tile[ns + k][c];
        short* dst = hT_bf + (size_t)b * C * N + (size_t)c * N + n0 + ns;
        *(short8*)dst = *(short8*)&v[0];
        *(short8*)(dst + 8) = *(short8*)&v[8];
    }
}

// -------- Phase B: flash attention, 32 i-rows/wave, exp2 domain --------
__global__ __launch_bounds__(256) void attn_kernel(
    const u64* __restrict__ msk,       // N x N/64
    const short* __restrict__ h_bf,    // B,N,C
    const short* __restrict__ hT_bf,   // B,C,N
    const short* __restrict__ a_srcb,  // N,C (x log2e)
    const float* __restrict__ e2,      // B,N (x log2e)
    float* __restrict__ part_y,        // [S,B,N,C] or out if mode
    float* __restrict__ part_m,        // [S,B,N]
    float* __restrict__ part_l,        // [S,B,N]
    int JS, int mode)
{
    __shared__ short lds_p[4][16 * 72];
    __shared__ float lds_e2[4][512];

    const int tid = threadIdx.x;
    const int wave = tid >> 6;
    const int lane = tid & 63;
    const int cl = lane & 15;
    const int rg = lane >> 4;
    const int b = wave;
    const int i0 = blockIdx.x * 32;
    const int jbeg = blockIdx.y * JS;
    const bool e2lds = (JS <= 512);

    if (e2lds) {
        for (int q = lane * 4; q < JS; q += 256)
            *(f32x4*)&lds_e2[wave][q] = *(const f32x4*)(e2 + (size_t)b * N + jbeg + q);
    }

    short8 bfr[2][2];
#pragma unroll
    for (int u = 0; u < 2; u++) {
        const short* hrow = h_bf + ((size_t)b * N + i0 + u * 16 + cl) * C;
        bfr[u][0] = *(const short8*)(hrow + rg * 8);
        bfr[u][1] = *(const short8*)(hrow + 32 + rg * 8);
    }

    const u64* mr[2] = {msk + (size_t)(i0 + cl) * (N / 64),
                        msk + (size_t)(i0 + 16 + cl) * (N / 64)};

    f32x4 yacc[2][4];
#pragma unroll
    for (int u = 0; u < 2; u++)
#pragma unroll
        for (int t = 0; t < 4; t++) { f32x4 z = {0.f, 0.f, 0.f, 0.f}; yacc[u][t] = z; }
    float m_s[2] = {-1e30f, -1e30f};
    float l_s[2] = {0.f, 0.f};

    for (int j0 = jbeg; j0 < jbeg + JS; j0 += 64) {
        short8 a0[4], a1[4];
#pragma unroll
        for (int t = 0; t < 4; t++) {
            const short* arow = a_srcb + (size_t)(j0 + t * 16 + cl) * C + rg * 8;
            a0[t] = *(const short8*)(arow);
            a1[t] = *(const short8*)(arow + 32);
        }
        f32x4 e2q[4];
#pragma unroll
        for (int t = 0; t < 4; t++) {
            if (e2lds) e2q[t] = *(const f32x4*)&lds_e2[wave][j0 - jbeg + t * 16 + rg * 4];
            else       e2q[t] = *(const f32x4*)(e2 + (size_t)b * N + j0 + t * 16 + rg * 4);
        }
        u64 mbits[2] = {mr[0][j0 >> 6], mr[1][j0 >> 6]};

        short8 pa[2][2];
#pragma unroll
        for (int u = 0; u < 2; u++) {
            // S^T + e2 via C-init: st[t][r] = (h_i . a_j) + e2[j],  j = j0+t*16+rg*4+r
            f32x4 st[4];
#pragma unroll
            for (int t = 0; t < 4; t++) {
                f32x4 z = MFMA16(a0[t], bfr[u][0], e2q[t]);
                z = MFMA16(a1[t], bfr[u][1], z);
                st[t] = z;
            }

            unsigned wlo = (unsigned)mbits[u], whi = (unsigned)(mbits[u] >> 32);
            float mx = -1e30f;
#pragma unroll
            for (int t = 0; t < 4; t++) {
                unsigned w = (t < 2) ? wlo : whi;
                unsigned sh = (t & 1) * 16 + rg * 4;
#pragma unroll
                for (int r = 0; r < 4; r++) {
                    float sv = st[t][r];
                    sv = (sv >= 0.f) ? sv : 0.01f * sv;
                    sv = ((w >> (sh + r)) & 1u) ? sv : -1e15f;
                    st[t][r] = sv;
                    mx = fmaxf(mx, sv);
                }
            }

            mx = fmaxf(mx, __shfl_xor(mx, 16, 64));
            mx = fmaxf(mx, __shfl_xor(mx, 32, 64));
            float mnew = fmaxf(m_s[u], mx);
            float alpha = exp2f(m_s[u] - mnew);
            m_s[u] = mnew;
            float ps = 0.f;
#pragma unroll
            for (int t = 0; t < 4; t++)
#pragma unroll
                for (int r = 0; r < 4; r++) {
                    float pv = exp2f(st[t][r] - mnew);
                    st[t][r] = pv;
                    ps += pv;
                }
            ps += __shfl_xor(ps, 16, 64);
            ps += __shfl_xor(ps, 32, 64);
            l_s[u] = l_s[u] * alpha + ps;

            // broadcast alpha of rows rg*4+r via bpermute (rows 0..15 live in lanes 0..15)
            float a4[4];
#pragma unroll
            for (int r = 0; r < 4; r++) a4[r] = __shfl(alpha, rg * 4 + r, 64);
#pragma unroll
            for (int t = 0; t < 4; t++)
#pragma unroll
                for (int r = 0; r < 4; r++) yacc[u][t][r] *= a4[r];

            // P -> LDS (packed cvt, one b64 store per t)
            short* lp = lds_p[wave];
#pragma unroll
            for (int t = 0; t < 4; t++) {
                uint2 pk = {pk2bf(st[t][0], st[t][1]), pk2bf(st[t][2], st[t][3])};
                *(uint2*)(lp + cl * 72 + t * 16 + rg * 4) = pk;
            }
            pa[u][0] = *(const short8*)(lp + cl * 72 + rg * 8);
            pa[u][1] = *(const short8*)(lp + cl * 72 + 32 + rg * 8);
        }

#pragma unroll
        for (int t = 0; t < 4; t++) {
            const short* hc = hT_bf + (size_t)b * C * N + (size_t)(t * 16 + cl) * N + j0 + rg * 8;
            short8 h0 = *(const short8*)(hc);
            short8 h1 = *(const short8*)(hc + 32);
            yacc[0][t] = MFMA16(pa[0][0], h0, yacc[0][t]);
            yacc[0][t] = MFMA16(pa[0][1], h1, yacc[0][t]);
            yacc[1][t] = MFMA16(pa[1][0], h0, yacc[1][t]);
            yacc[1][t] = MFMA16(pa[1][1], h1, yacc[1][t]);
        }
    }

    if (mode) {
#pragma unroll
        for (int u = 0; u < 2; u++) {
            float l4[4];
#pragma unroll
            for (int r = 0; r < 4; r++) l4[r] = __shfl(l_s[u], rg * 4 + r, 64);
#pragma unroll
            for (int t = 0; t < 4; t++)
#pragma unroll
                for (int r = 0; r < 4; r++)
                    part_y[((size_t)b * N + i0 + u * 16 + rg * 4 + r) * C + t * 16 + cl] =
                        yacc[u][t][r] / l4[r];
        }
    } else {
        size_t sb = (size_t)(blockIdx.y * B + b) * N;
#pragma unroll
        for (int u = 0; u < 2; u++) {
#pragma unroll
            for (int t = 0; t < 4; t++)
#pragma unroll
                for (int r = 0; r < 4; r++)
                    part_y[(sb + i0 + u * 16 + rg * 4 + r) * C + t * 16 + cl] = yacc[u][t][r];
            if (lane < 16) {
                part_m[sb + i0 + u * 16 + lane] = m_s[u];
                part_l[sb + i0 + u * 16 + lane] = l_s[u];
            }
        }
    }
}

// -------- merge stripes (m's are in log2 domain -> exp2) --------
__global__ __launch_bounds__(256) void combine_kernel(
    const float* __restrict__ part_y, const float* __restrict__ part_m,
    const float* __restrict__ part_l, float* __restrict__ out, int S)
{
    int g = blockIdx.x * 256 + threadIdx.x;
    int c = g & 63;
    int row = (g >> 6) & (N - 1);
    int b = g >> 18;
    int bn = b * N + row;
    float m = -1e30f;
    for (int s = 0; s < S; s++) m = fmaxf(m, part_m[s * (B * N) + bn]);
    float l = 0.f, y = 0.f;
    for (int s = 0; s < S; s++) {
        float w = exp2f(part_m[s * (B * N) + bn] - m);
        l += part_l[s * (B * N) + bn] * w;
        y += part_y[((size_t)s * B * N + bn) * C + c] * w;
    }
    out[g] = y / l;
}

extern "C" void kernel_launch(void* const* d_in, const int* in_sizes, int n_in,
                              void* d_out, int out_size, void* d_ws, size_t ws_size,
                              hipStream_t stream) {
    const float* x      = (const float*)d_in[0];
    const float* dist   = (const float*)d_in[1];
    const float* proj_w = (const float*)d_in[2];
    const float* proj_b = (const float*)d_in[3];
    const float* a_w    = (const float*)d_in[4];
    float* out = (float*)d_out;

    char* ws = (char*)d_ws;
    short* h_bf   = (short*)(ws);                              // 2 MB
    short* hT_bf  = (short*)(ws + (2u << 20));                 // 2 MB
    short* a_srcb = (short*)(ws + (4u << 20));                 // 512 KB
    float* e2     = (float*)(ws + (4u << 20) + (512u << 10));  // 64 KB
    u64*   msk    = (u64*)  (ws + (5u << 20));                 // 2 MB
    float* part_m = (float*)(ws + (7u << 20));                 // 1 MB (S=16)
    float* part_l = (float*)(ws + (7u << 20) + (1u << 20));    // 1 MB
    float* part_y = (float*)(ws + (9u << 20));                 // S * 4 MB

    proj_mask_kernel<<<N / 2, 256, 0, stream>>>(x, proj_w, proj_b, a_w, dist,
                                                h_bf, a_srcb, e2, msk);
    transpose_kernel<<<dim3(N / 64, B), 256, 0, stream>>>(h_bf, hT_bf);

    int S = 16;
    while (S > 1 && (9u << 20) + (size_t)S * B * N * C * 4 > ws_size) S >>= 1;
    bool direct = ((9u << 20) + (size_t)B * N * C * 4 > ws_size);

    if (direct) {
        attn_kernel<<<dim3(N / 32, 1), 256, 0, stream>>>(
            msk, h_bf, hT_bf, a_srcb, e2, out, part_m, part_l, N, 1);
    } else {
        attn_kernel<<<dim3(N / 32, S), 256, 0, stream>>>(
            msk, h_bf, hT_bf, a_srcb, e2, part_y, part_m, part_l, N / S, 0);
        combine_kernel<<<(B * N * C) / 256, 256, 0, stream>>>(part_y, part_m, part_l, out, S);
    }
}

// Round 8
// 303.229 us; speedup vs baseline: 1.0574x; 1.0574x over previous
//
#include <hip/hip_runtime.h>

#define N 4096
#define C 64
#define B 4
#define LOG2E 1.44269504088896340736f

typedef __attribute__((ext_vector_type(8))) short short8;
typedef __attribute__((ext_vector_type(4))) short s16x4;
typedef __attribute__((ext_vector_type(4))) float f32x4;
typedef unsigned long long u64;

#define MFMA16(a, b, c) __builtin_amdgcn_mfma_f32_16x16x32_bf16(a, b, c, 0, 0, 0)

__device__ __forceinline__ short f2bf(float f) {
    unsigned u = __builtin_bit_cast(unsigned, f);
    u += 0x7fffu + ((u >> 16) & 1u);   // RNE; inputs finite
    return (short)(u >> 16);
}
__device__ __forceinline__ unsigned pk2bf(float a, float b) {
    unsigned lo = (unsigned)(unsigned short)f2bf(a);
    unsigned hi = (unsigned)(unsigned short)f2bf(b);
    return lo | (hi << 16);
}

// -------- Fused Phase A --------
// blocks [0, N/4): projection, 4 nodes/block, W double-buffered through LDS
//   (stream: issue next node's loads BEFORE computing current -> high mem duty cycle)
// blocks [N/4, N/2): adjacency bitmask, unroll-16 scalar loads
// a_srcb and e2 PRE-SCALED by log2e (attn uses exp2).
__global__ __launch_bounds__(256) void proj_mask_kernel(
    const float* __restrict__ x,       // B,N,C
    const float* __restrict__ proj_w,  // N,C,C
    const float* __restrict__ proj_b,  // N,C
    const float* __restrict__ a_w,     // N,2C
    const float* __restrict__ dist,    // N,N
    short* __restrict__ h_bf,          // B,N,C
    short* __restrict__ a_srcb,        // N,C  (x log2e)
    float* __restrict__ e2,            // B,N  (x log2e)
    u64* __restrict__ msk)             // N x N/64
{
    __shared__ float lds_w[2][4096];   // 2 x 16 KB double buffer
    __shared__ float lds_x[4][B][C];   // x rows for the block's 4 nodes

    const int tid = threadIdx.x;
    const int wave = tid >> 6;
    const int lane = tid & 63;

    if (blockIdx.x >= N / 4) {
        // ---- mask branch ----
        const int i = (blockIdx.x - N / 4) * 4 + wave;
        const float* row = dist + (size_t)i * N;
#pragma unroll 16
        for (int jb = 0; jb < N / 64; jb++) {
            float d = row[jb * 64 + lane];
            u64 m = __ballot(d > 0.f && d < 0.5f);
            int dj = i - jb * 64;
            if (dj >= 0 && dj < 64) m |= (1ull << dj);
            if (lane == 0) msk[(size_t)i * (N / 64) + jb] = m;
        }
        return;
    }

    // ---- proj branch ----
    const int n0 = blockIdx.x * 4;
    const int og = lane & 15;   // output quad: o = og*4..og*4+3
    const int p = lane >> 4;    // c-phase 0..3
    const int b = wave;

    // stage x for all 4 nodes (wave = b, lane = c)
#pragma unroll
    for (int k = 0; k < 4; k++)
        lds_x[k][b][lane] = x[((size_t)b * N + n0 + k) * C + lane];

    // stage W for node 0
    {
        const float* W0 = proj_w + (size_t)n0 * (C * C);
#pragma unroll
        for (int q = 0; q < 4; q++)
            *(float4*)&lds_w[0][q * 1024 + tid * 4] = *(const float4*)(W0 + q * 1024 + tid * 4);
    }
    __syncthreads();

#pragma unroll
    for (int k = 0; k < 4; k++) {
        // issue next node's W loads first -> they fly during compute(k)
        float4 wb[4];
        if (k < 3) {
            const float* W1 = proj_w + (size_t)(n0 + k + 1) * (C * C);
#pragma unroll
            for (int q = 0; q < 4; q++)
                wb[q] = *(const float4*)(W1 + q * 1024 + tid * 4);
        }

        // compute node k: acc[q] = sum_c x[b][c] * W[c][og*4+q],  c = 4i+p
        const float* lw = lds_w[k & 1];
        f32x4 acc = {0.f, 0.f, 0.f, 0.f};
#pragma unroll
        for (int i = 0; i < 16; i++) {
            float xb = lds_x[k][b][4 * i + p];                      // broadcast read
            f32x4 w4 = *(const f32x4*)&lw[(4 * i + p) * C + og * 4]; // b128, conflict-free
#pragma unroll
            for (int q = 0; q < 4; q++) acc[q] = fmaf(xb, w4[q], acc[q]);
        }
        // reduce over the 4 c-phases
#pragma unroll
        for (int q = 0; q < 4; q++) {
            acc[q] += __shfl_xor(acc[q], 16, 64);
            acc[q] += __shfl_xor(acc[q], 32, 64);
        }

        const int n = n0 + k;
        if (lane < 16) {   // p==0 lanes hold the full sums; og = lane
            f32x4 pb4 = *(const f32x4*)(proj_b + (size_t)n * C + og * 4);
            f32x4 h4;
#pragma unroll
            for (int q = 0; q < 4; q++) h4[q] = acc[q] + pb4[q];
            uint2 pk = {pk2bf(h4[0], h4[1]), pk2bf(h4[2], h4[3])};
            *(uint2*)(h_bf + ((size_t)b * N + n) * C + og * 4) = pk;
            f32x4 ad4 = *(const f32x4*)(a_w + (size_t)n * (2 * C) + C + og * 4);
            float ep = (h4[0] * ad4[0] + h4[1] * ad4[1] + h4[2] * ad4[2] + h4[3] * ad4[3]) * LOG2E;
#pragma unroll
            for (int off = 1; off < 16; off <<= 1) ep += __shfl_xor(ep, off, 64);
            if (og == 0) e2[(size_t)b * N + n] = ep;
        }
        if (wave == 0)
            a_srcb[(size_t)n * C + lane] = f2bf(a_w[(size_t)n * (2 * C) + lane] * LOG2E);

        // park next node's W into the other buffer (loads have landed by now)
        if (k < 3) {
#pragma unroll
            for (int q = 0; q < 4; q++)
                *(float4*)&lds_w[(k + 1) & 1][q * 1024 + tid * 4] = wb[q];
        }
        __syncthreads();
    }
}

// -------- h (B,N,C) -> hT (B,C,N) --------
__global__ __launch_bounds__(256) void transpose_kernel(const short* __restrict__ h_bf,
                                                        short* __restrict__ hT_bf) {
    __shared__ short tile[64][72];
    const int t = threadIdx.x;
    const int b = blockIdx.y;
    const int n0 = blockIdx.x * 64;
    {
        int r = t >> 2, cs = (t & 3) * 16;
        const short* src = h_bf + ((size_t)b * N + n0 + r) * C + cs;
#pragma unroll
        for (int q = 0; q < 4; q++)
            *(s16x4*)&tile[r][cs + q * 4] = *(const s16x4*)(src + q * 4);
    }
    __syncthreads();
    {
        int c = t >> 2, ns = (t & 3) * 16;
        short v[16];
#pragma unroll
        for (int k = 0; k < 16; k++) v[k] = tile[ns + k][c];
        short* dst = hT_bf + (size_t)b * C * N + (size_t)c * N + n0 + ns;
        *(short8*)dst = *(short8*)&v[0];
        *(short8*)(dst + 8) = *(short8*)&v[8];
    }
}

// -------- Phase B: flash attention, 32 i-rows/wave, exp2 domain --------
__global__ __launch_bounds__(256) void attn_kernel(
    const u64* __restrict__ msk,       // N x N/64
    const short* __restrict__ h_bf,    // B,N,C
    const short* __restrict__ hT_bf,   // B,C,N
    const short* __restrict__ a_srcb,  // N,C (x log2e)
    const float* __restrict__ e2,      // B,N (x log2e)
    float* __restrict__ part_y,        // [S,B,N,C] or out if mode
    float* __restrict__ part_m,        // [S,B,N]
    float* __restrict__ part_l,        // [S,B,N]
    int JS, int mode)
{
    __shared__ short lds_p[4][16 * 72];
    __shared__ float lds_e2[4][512];

    const int tid = threadIdx.x;
    const int wave = tid >> 6;
    const int lane = tid & 63;
    const int cl = lane & 15;
    const int rg = lane >> 4;
    const int b = wave;
    const int i0 = blockIdx.x * 32;
    const int jbeg = blockIdx.y * JS;
    const bool e2lds = (JS <= 512);

    if (e2lds) {
        for (int q = lane * 4; q < JS; q += 256)
            *(f32x4*)&lds_e2[wave][q] = *(const f32x4*)(e2 + (size_t)b * N + jbeg + q);
    }

    short8 bfr[2][2];
#pragma unroll
    for (int u = 0; u < 2; u++) {
        const short* hrow = h_bf + ((size_t)b * N + i0 + u * 16 + cl) * C;
        bfr[u][0] = *(const short8*)(hrow + rg * 8);
        bfr[u][1] = *(const short8*)(hrow + 32 + rg * 8);
    }

    const u64* mr[2] = {msk + (size_t)(i0 + cl) * (N / 64),
                        msk + (size_t)(i0 + 16 + cl) * (N / 64)};

    f32x4 yacc[2][4];
#pragma unroll
    for (int u = 0; u < 2; u++)
#pragma unroll
        for (int t = 0; t < 4; t++) { f32x4 z = {0.f, 0.f, 0.f, 0.f}; yacc[u][t] = z; }
    float m_s[2] = {-1e30f, -1e30f};
    float l_s[2] = {0.f, 0.f};

    for (int j0 = jbeg; j0 < jbeg + JS; j0 += 64) {
        short8 a0[4], a1[4];
#pragma unroll
        for (int t = 0; t < 4; t++) {
            const short* arow = a_srcb + (size_t)(j0 + t * 16 + cl) * C + rg * 8;
            a0[t] = *(const short8*)(arow);
            a1[t] = *(const short8*)(arow + 32);
        }
        f32x4 e2q[4];
#pragma unroll
        for (int t = 0; t < 4; t++) {
            if (e2lds) e2q[t] = *(const f32x4*)&lds_e2[wave][j0 - jbeg + t * 16 + rg * 4];
            else       e2q[t] = *(const f32x4*)(e2 + (size_t)b * N + j0 + t * 16 + rg * 4);
        }
        u64 mbits[2] = {mr[0][j0 >> 6], mr[1][j0 >> 6]};

        short8 pa[2][2];
#pragma unroll
        for (int u = 0; u < 2; u++) {
            f32x4 st[4];
#pragma unroll
            for (int t = 0; t < 4; t++) {
                f32x4 z = MFMA16(a0[t], bfr[u][0], e2q[t]);
                z = MFMA16(a1[t], bfr[u][1], z);
                st[t] = z;
            }

            unsigned wlo = (unsigned)mbits[u], whi = (unsigned)(mbits[u] >> 32);
            float mx = -1e30f;
#pragma unroll
            for (int t = 0; t < 4; t++) {
                unsigned w = (t < 2) ? wlo : whi;
                unsigned sh = (t & 1) * 16 + rg * 4;
#pragma unroll
                for (int r = 0; r < 4; r++) {
                    float sv = st[t][r];
                    sv = (sv >= 0.f) ? sv : 0.01f * sv;
                    sv = ((w >> (sh + r)) & 1u) ? sv : -1e15f;
                    st[t][r] = sv;
                    mx = fmaxf(mx, sv);
                }
            }

            mx = fmaxf(mx, __shfl_xor(mx, 16, 64));
            mx = fmaxf(mx, __shfl_xor(mx, 32, 64));
            float mnew = fmaxf(m_s[u], mx);
            float alpha = exp2f(m_s[u] - mnew);
            m_s[u] = mnew;
            float ps = 0.f;
#pragma unroll
            for (int t = 0; t < 4; t++)
#pragma unroll
                for (int r = 0; r < 4; r++) {
                    float pv = exp2f(st[t][r] - mnew);
                    st[t][r] = pv;
                    ps += pv;
                }
            ps += __shfl_xor(ps, 16, 64);
            ps += __shfl_xor(ps, 32, 64);
            l_s[u] = l_s[u] * alpha + ps;

            float a4[4];
#pragma unroll
            for (int r = 0; r < 4; r++) a4[r] = __shfl(alpha, rg * 4 + r, 64);
#pragma unroll
            for (int t = 0; t < 4; t++)
#pragma unroll
                for (int r = 0; r < 4; r++) yacc[u][t][r] *= a4[r];

            short* lp = lds_p[wave];
#pragma unroll
            for (int t = 0; t < 4; t++) {
                uint2 pk = {pk2bf(st[t][0], st[t][1]), pk2bf(st[t][2], st[t][3])};
                *(uint2*)(lp + cl * 72 + t * 16 + rg * 4) = pk;
            }
            pa[u][0] = *(const short8*)(lp + cl * 72 + rg * 8);
            pa[u][1] = *(const short8*)(lp + cl * 72 + 32 + rg * 8);
        }

#pragma unroll
        for (int t = 0; t < 4; t++) {
            const short* hc = hT_bf + (size_t)b * C * N + (size_t)(t * 16 + cl) * N + j0 + rg * 8;
            short8 h0 = *(const short8*)(hc);
            short8 h1 = *(const short8*)(hc + 32);
            yacc[0][t] = MFMA16(pa[0][0], h0, yacc[0][t]);
            yacc[0][t] = MFMA16(pa[0][1], h1, yacc[0][t]);
            yacc[1][t] = MFMA16(pa[1][0], h0, yacc[1][t]);
            yacc[1][t] = MFMA16(pa[1][1], h1, yacc[1][t]);
        }
    }

    if (mode) {
#pragma unroll
        for (int u = 0; u < 2; u++) {
            float l4[4];
#pragma unroll
            for (int r = 0; r < 4; r++) l4[r] = __shfl(l_s[u], rg * 4 + r, 64);
#pragma unroll
            for (int t = 0; t < 4; t++)
#pragma unroll
                for (int r = 0; r < 4; r++)
                    part_y[((size_t)b * N + i0 + u * 16 + rg * 4 + r) * C + t * 16 + cl] =
                        yacc[u][t][r] / l4[r];
        }
    } else {
        size_t sb = (size_t)(blockIdx.y * B + b) * N;
#pragma unroll
        for (int u = 0; u < 2; u++) {
#pragma unroll
            for (int t = 0; t < 4; t++)
#pragma unroll
                for (int r = 0; r < 4; r++)
                    part_y[(sb + i0 + u * 16 + rg * 4 + r) * C + t * 16 + cl] = yacc[u][t][r];
            if (lane < 16) {
                part_m[sb + i0 + u * 16 + lane] = m_s[u];
                part_l[sb + i0 + u * 16 + lane] = l_s[u];
            }
        }
    }
}

// -------- merge stripes (log2 domain) --------
__global__ __launch_bounds__(256) void combine_kernel(
    const float* __restrict__ part_y, const float* __restrict__ part_m,
    const float* __restrict__ part_l, float* __restrict__ out, int S)
{
    int g = blockIdx.x * 256 + threadIdx.x;
    int c = g & 63;
    int row = (g >> 6) & (N - 1);
    int b = g >> 18;
    int bn = b * N + row;
    float m = -1e30f;
    for (int s = 0; s < S; s++) m = fmaxf(m, part_m[s * (B * N) + bn]);
    float l = 0.f, y = 0.f;
    for (int s = 0; s < S; s++) {
        float w = exp2f(part_m[s * (B * N) + bn] - m);
        l += part_l[s * (B * N) + bn] * w;
        y += part_y[((size_t)s * B * N + bn) * C + c] * w;
    }
    out[g] = y / l;
}

extern "C" void kernel_launch(void* const* d_in, const int* in_sizes, int n_in,
                              void* d_out, int out_size, void* d_ws, size_t ws_size,
                              hipStream_t stream) {
    const float* x      = (const float*)d_in[0];
    const float* dist   = (const float*)d_in[1];
    const float* proj_w = (const float*)d_in[2];
    const float* proj_b = (const float*)d_in[3];
    const float* a_w    = (const float*)d_in[4];
    float* out = (float*)d_out;

    char* ws = (char*)d_ws;
    short* h_bf   = (short*)(ws);                              // 2 MB
    short* hT_bf  = (short*)(ws + (2u << 20));                 // 2 MB
    short* a_srcb = (short*)(ws + (4u << 20));                 // 512 KB
    float* e2     = (float*)(ws + (4u << 20) + (512u << 10));  // 64 KB
    u64*   msk    = (u64*)  (ws + (5u << 20));                 // 2 MB
    float* part_m = (float*)(ws + (7u << 20));                 // 512 KB (S=8)
    float* part_l = (float*)(ws + (7u << 20) + (512u << 10));  // 512 KB
    float* part_y = (float*)(ws + (8u << 20));                 // S * 4 MB

    proj_mask_kernel<<<N / 2, 256, 0, stream>>>(x, proj_w, proj_b, a_w, dist,
                                                h_bf, a_srcb, e2, msk);
    transpose_kernel<<<dim3(N / 64, B), 256, 0, stream>>>(h_bf, hT_bf);

    int S = 8;
    while (S > 1 && (8u << 20) + (size_t)S * B * N * C * 4 > ws_size) S >>= 1;
    bool direct = ((8u << 20) + (size_t)B * N * C * 4 > ws_size);

    if (direct) {
        attn_kernel<<<dim3(N / 32, 1), 256, 0, stream>>>(
            msk, h_bf, hT_bf, a_srcb, e2, out, part_m, part_l, N, 1);
    } else {
        attn_kernel<<<dim3(N / 32, S), 256, 0, stream>>>(
            msk, h_bf, hT_bf, a_srcb, e2, part_y, part_m, part_l, N / S, 0);
        combine_kernel<<<(B * N * C) / 256, 256, 0, stream>>>(part_y, part_m, part_l, out, S);
    }
}